// Round 12
// baseline (232.517 us; speedup 1.0000x reference)
//
#include <hip/hip_runtime.h>
#include <hip/hip_bf16.h>

typedef __hip_bfloat16 bf16;

// flags[0] = 1 if floats are f32 (else bf16); flags[1] = 1 if ints are int64 (else int32)
static __device__ __forceinline__ float loadF(const void* p, long long i, int f32){
  return f32 ? ((const float*)p)[i] : __bfloat162float(((const bf16*)p)[i]);
}
static __device__ __forceinline__ int loadI(const void* p, long long i, int i64){
  return i64 ? (int)((const long long*)p)[i] : ((const int*)p)[i];
}
// round-to-nearest-even float -> bf16 bits (finite inputs)
static __device__ __forceinline__ unsigned short f2bf(float f){
  unsigned u = __float_as_uint(f);
  return (unsigned short)((u + 0x7FFFu + ((u>>16)&1u)) >> 16);
}
static __device__ __forceinline__ float bf2f(unsigned v){
  return __uint_as_float(v<<16);
}

#define CAP 4096        // log entries per bucket (avg ~1023; padded avg ~1215)
#define LB_EDGES 4096   // edges per logbuild block

// g tables are plane-split: plane p in {0,1} holds feats [32p, 32p+32) as 16 dwords/row,
// rows 0..N (row N = zero sentinel for csr padding). Plane stride PS = (N+1)*16 dwords.

// ---------------- init: zero cursors + S + sentinel rows + dtype sniff (block 0) ----------------
__global__ void k_init(const unsigned int* __restrict__ xw, const unsigned int* __restrict__ eiw,
                       int* __restrict__ flags, int* __restrict__ gcursor, int nbuckets,
                       float* __restrict__ S, int gn,
                       unsigned int* __restrict__ g0, unsigned int* __restrict__ g1, int N){
  int i = blockIdx.x*256 + threadIdx.x;
  if(i < nbuckets) gcursor[i] = 0;
  if(i < gn) S[i] = 0.f;
  if(blockIdx.x == 0){
    if(threadIdx.x < 32){                              // zero sentinel row N in both planes
      long long PS = (long long)(N+1)*16;
      int p = threadIdx.x>>4, off = threadIdx.x&15;
      g0[(long long)p*PS + (long long)N*16 + off] = 0u;
      g1[(long long)p*PS + (long long)N*16 + off] = 0u;
    }
    __shared__ int s1, s2;
    if(threadIdx.x==0){ s1=0; s2=0; }
    __syncthreads();
    unsigned w = xw[threadIdx.x];
    int e = (int)((w>>7)&0xFFu);
    if(e>=110 && e<=135) atomicAdd(&s1, 1);            // bf16-pair exponent signature
    if(eiw[2*threadIdx.x+1] != 0u) atomicAdd(&s2, 1);  // int64 high words
    __syncthreads();
    if(threadIdx.x==0){
      flags[0] = (s1 < 128) ? 1 : 0;   // 1 => f32
      flags[1] = (s2 < 128) ? 1 : 0;   // 1 => int64
    }
  }
}

// ---------------- bucket-log build: packed (dst<<16)|src, grouped by dst>>6 ----------------
__global__ __launch_bounds__(256) void k_logbuild(const void* __restrict__ ei, int E, int N,
                                                  const int* __restrict__ flags,
                                                  int* __restrict__ gcursor,
                                                  unsigned int* __restrict__ log, int nbuckets){
  __shared__ unsigned int stash[LB_EDGES];   // 16 KB
  __shared__ int hcnt[1024];
  __shared__ int hbase[1024];
  int t = threadIdx.x;
  for(int b=t; b<nbuckets; b+=256) hcnt[b] = 0;
  __syncthreads();
  int i64 = flags[1];
  long long e0 = (long long)blockIdx.x*LB_EDGES;
  int cnt = (int)(((long long)E - e0) < LB_EDGES ? ((long long)E - e0) : LB_EDGES);
  for(int k=t; k<cnt; k+=256){
    long long e = e0 + k;
    int s = loadI(ei, e, i64);                 s = min(max(s,0), N-1);
    int d = loadI(ei, (long long)E + e, i64);  d = min(max(d,0), N-1);
    unsigned p = (((unsigned)d)<<16) | (unsigned)s;   // requires N <= 65535
    stash[k] = p;
    atomicAdd(&hcnt[d>>6], 1);
  }
  __syncthreads();
  for(int b=t; b<nbuckets; b+=256){
    int c = hcnt[b];
    hbase[b] = (c>0) ? atomicAdd(&gcursor[b], c) : 0;
    hcnt[b] = 0;
  }
  __syncthreads();
  for(int k=t; k<cnt; k+=256){
    unsigned p = stash[k];
    int b = (int)(p>>22);                      // dst>>6
    int pos = hbase[b] + atomicAdd(&hcnt[b], 1);
    if(pos < CAP) log[(long long)b*CAP + pos] = p;
  }
}

// ---------------- per-bucket counting sort (padded to x4 with sentinel N) + dinv + g0 planes ----------------
__global__ __launch_bounds__(256) void k_bsortg0(const unsigned int* __restrict__ log,
                                                 const int* __restrict__ gcursor,
                                                 unsigned short* __restrict__ csr,
                                                 int* __restrict__ beg, int* __restrict__ endv,
                                                 float* __restrict__ dinv,
                                                 const void* __restrict__ x, const int* __restrict__ flags,
                                                 unsigned int* __restrict__ g0, int N){
  __shared__ int hist[64];
  __shared__ int cur[64];
  __shared__ float dloc[64];
  int b = blockIdx.x, t = threadIdx.x;
  if(t < 64) hist[t] = 0;
  __syncthreads();
  int n = min(gcursor[b], CAP);
  const unsigned int* L = log + (long long)b*CAP;
  for(int j=t; j<n; j+=256) atomicAdd(&hist[(L[j]>>16)&63], 1);
  __syncthreads();
  if(t < 64){                                   // wave 0: exclusive scan over padded counts
    int v = hist[t];
    int vp = (v + 3) & ~3;                      // padded to multiple of 4
    int inc = vp;
    #pragma unroll
    for(int o=1; o<64; o<<=1){
      int u = __shfl_up(inc, o);
      if(t >= o) inc += u;
    }
    int excl = inc - vp;
    cur[t] = excl;
    float dv = rsqrtf((float)(v + 1));          // +1 = self loop
    dloc[t] = dv;
    int node = b*64 + t;
    if(node < N){
      beg[node]  = b*CAP + excl;
      endv[node] = b*CAP + excl + v;            // true end; agg pads to x4 via sentinel
      dinv[node] = dv;
    }
    unsigned short* C = csr + (long long)b*CAP; // sentinel pad fill (disjoint from placements)
    for(int q=v; q<vp; q++) C[excl+q] = (unsigned short)N;
  }
  __syncthreads();
  unsigned short* C = csr + (long long)b*CAP;
  for(int j=t; j<n; j+=256){
    unsigned p = L[j];
    int l = (int)((p>>16)&63u);
    int pos = atomicAdd(&cur[l], 1);
    C[pos] = (unsigned short)(p & 0xFFFFu);
  }
  // g0 planes for this bucket's nodes: g0 = bf16(x * dinv)
  int f32 = flags[0];
  long long PS = (long long)(N+1)*16;
  long long xbase = (long long)b*64*64;
  for(int i=t; i<2048; i+=256){                 // 2048 dwords = 64 rows x 32 dwords
    int nl = i>>5, fd = i&31;
    int node = b*64 + nl;
    if(node < N){
      int p = fd>>4, off = fd&15;
      float u0 = loadF(x, xbase + nl*64 + 2*fd,     f32) * dloc[nl];
      float u1 = loadF(x, xbase + nl*64 + 2*fd + 1, f32) * dloc[nl];
      g0[(long long)p*PS + (long long)node*16 + off] = (unsigned)f2bf(u0) | ((unsigned)f2bf(u1)<<16);
    }
  }
}

// ---------------- AGG (plane): a[d] = bf16( dinv[d]*(sum nbrs + self) ), 32 feats per wave ----------------
// wave per (node, plane); 16 lanes x 4 edges per gather instruction; 4 loads in flight
__global__ __launch_bounds__(256) void k_agg(const unsigned int* __restrict__ Gt,
                                             const unsigned short* __restrict__ csr,
                                             const int* __restrict__ beg, const int* __restrict__ endv,
                                             const float* __restrict__ dinv,
                                             unsigned int* __restrict__ out32, int N, int nbpp){
  int plane = (blockIdx.x >= nbpp) ? 1 : 0;
  int node = (blockIdx.x - plane*nbpp)*4 + (threadIdx.x>>6);
  if(node >= N) return;
  int lane = threadIdx.x&63;
  int fl = lane&15, eo = lane>>4;               // dword-in-row, edge offset 0..3
  long long PS = (long long)(N+1)*16;
  const unsigned int* G = Gt + (long long)plane*PS;
  int j = beg[node], e = endv[node];
  int ep = j + ((e - j + 3) & ~3);              // padded end (sentinels -> zero row N)
  float2 c0={0.f,0.f}, c1={0.f,0.f}, c2={0.f,0.f}, c3={0.f,0.f};
  for(; j+16<=ep; j+=16){                       // 16 edges / iter, 4 gathers in flight
    int s0 = csr[j      + eo];
    int s1 = csr[j + 4  + eo];
    int s2 = csr[j + 8  + eo];
    int s3 = csr[j + 12 + eo];
    unsigned v0 = G[(long long)s0*16 + fl];
    unsigned v1 = G[(long long)s1*16 + fl];
    unsigned v2 = G[(long long)s2*16 + fl];
    unsigned v3 = G[(long long)s3*16 + fl];
    c0.x += bf2f(v0 & 0xFFFFu); c0.y += bf2f(v0 >> 16);
    c1.x += bf2f(v1 & 0xFFFFu); c1.y += bf2f(v1 >> 16);
    c2.x += bf2f(v2 & 0xFFFFu); c2.y += bf2f(v2 >> 16);
    c3.x += bf2f(v3 & 0xFFFFu); c3.y += bf2f(v3 >> 16);
  }
  for(; j<ep; j+=4){                            // 4-edge tail
    int s = csr[j + eo];
    unsigned v = G[(long long)s*16 + fl];
    c0.x += bf2f(v & 0xFFFFu); c0.y += bf2f(v >> 16);
  }
  float sx = (c0.x+c1.x)+(c2.x+c3.x);
  float sy = (c0.y+c1.y)+(c2.y+c3.y);
  sx += __shfl_xor(sx, 16, 64); sx += __shfl_xor(sx, 32, 64);
  sy += __shfl_xor(sy, 16, 64); sy += __shfl_xor(sy, 32, 64);
  if(eo == 0){
    unsigned sv = G[(long long)node*16 + fl];   // self term
    float dv = dinv[node];
    float ox = (sx + bf2f(sv & 0xFFFFu)) * dv;
    float oy = (sy + bf2f(sv >> 16)) * dv;
    out32[(long long)node*32 + plane*16 + fl] = (unsigned)f2bf(ox) | ((unsigned)f2bf(oy) << 16);
  }
}

// ---------------- GEMM1: g1 = bf16(relu(a @ W1 + b1) * dinv[row]) -> plane layout ----------------
// tile: 128 rows x 64 cols, 256 threads, R=8 C=4 per thread; a (aBuf) is linear bf16
__global__ __launch_bounds__(256) void k_gemm1(const unsigned int* __restrict__ A32, const void* __restrict__ W,
                                               const void* __restrict__ b, const int* __restrict__ flags,
                                               const float* __restrict__ dinv, unsigned int* __restrict__ g1, int N){
  __shared__ float Ws[64*64];
  __shared__ float xs[128*65];
  int f32 = flags[0];
  int tid = threadIdx.x;
  for(int i=tid;i<4096;i+=256) Ws[i] = loadF(W, i, f32);
  int row0 = blockIdx.x*128;
  for(int i=tid;i<4096;i+=256){                 // 4096 dwords = 128 rows x 32 dwords
    int r = i>>5, kd = i&31;
    int gr = row0 + r;
    unsigned v = (gr<N) ? A32[(long long)gr*32 + kd] : 0u;
    xs[r*65 + 2*kd    ] = bf2f(v & 0xFFFFu);
    xs[r*65 + 2*kd + 1] = bf2f(v >> 16);
  }
  __syncthreads();
  int cg = tid&15, rg = tid>>4;
  int col_g = cg*4, row_g = rg*8;
  float acc[8][4];
  #pragma unroll
  for(int r=0;r<8;r++){ acc[r][0]=0.f; acc[r][1]=0.f; acc[r][2]=0.f; acc[r][3]=0.f; }
  for(int k=0;k<64;k++){
    float4 w = *(const float4*)&Ws[k*64 + col_g];
    float xr[8];
    #pragma unroll
    for(int r=0;r<8;r++) xr[r] = xs[(row_g+r)*65 + k];
    #pragma unroll
    for(int r=0;r<8;r++){
      acc[r][0] += xr[r]*w.x; acc[r][1] += xr[r]*w.y;
      acc[r][2] += xr[r]*w.z; acc[r][3] += xr[r]*w.w;
    }
  }
  float b0 = loadF(b, col_g,   f32), b1v = loadF(b, col_g+1, f32);
  float b2v = loadF(b, col_g+2, f32), b3 = loadF(b, col_g+3, f32);
  long long PS = (long long)(N+1)*16;
  int p = (col_g >= 32) ? 1 : 0;
  int off = (col_g & 31) >> 1;                  // dword offset in plane row (even -> 8B aligned)
  #pragma unroll
  for(int r=0;r<8;r++){
    int gr = row0 + row_g + r;
    if(gr<N){
      float dv = dinv[gr];
      float v0 = acc[r][0]+b0, v1 = acc[r][1]+b1v, v2 = acc[r][2]+b2v, v3 = acc[r][3]+b3;
      v0 = (v0>0.f?v0:0.f)*dv; v1 = (v1>0.f?v1:0.f)*dv;
      v2 = (v2>0.f?v2:0.f)*dv; v3 = (v3>0.f?v3:0.f)*dv;
      uint2 st;
      st.x = (unsigned)f2bf(v0) | ((unsigned)f2bf(v1) << 16);
      st.y = (unsigned)f2bf(v2) | ((unsigned)f2bf(v3) << 16);
      *(uint2*)&g1[(long long)p*PS + (long long)gr*16 + off] = st;
    }
  }
}

// ---------------- fused GEMM2 + relu + fcW-dot + mean-pool partials; a (aBuf) linear bf16 ----------------
// tile: 128 rows x 128 cols; thread covers 8 rows x cols {4cg..4cg+3, 64+4cg..+3}
__global__ __launch_bounds__(256) void k_gemm2pool(const unsigned int* __restrict__ A32, const void* __restrict__ W,
                                                   const void* __restrict__ b, const void* __restrict__ fcW,
                                                   const void* __restrict__ batch, const int* __restrict__ flags,
                                                   float* __restrict__ S, int N, int NOUT){
  __shared__ float Ws[64*128];     // 32 KB
  __shared__ float xs[128*65];     // 32.5 KB
  __shared__ float Sloc[128*4];
  __shared__ int gid[128];
  int f32 = flags[0], i64 = flags[1];
  int tid = threadIdx.x;
  int row0 = blockIdx.x*128;
  for(int i=tid;i<8192;i+=256) Ws[i] = loadF(W, i, f32);
  for(int i=tid;i<4096;i+=256){
    int r = i>>5, kd = i&31;
    int gr = row0 + r;
    unsigned v = (gr<N) ? A32[(long long)gr*32 + kd] : 0u;
    xs[r*65 + 2*kd    ] = bf2f(v & 0xFFFFu);
    xs[r*65 + 2*kd + 1] = bf2f(v >> 16);
  }
  if(tid < 128){
    int node = row0 + tid;
    gid[tid] = (node < N) ? loadI(batch, node, i64) : 0;
  }
  for(int i=tid;i<512;i+=256) Sloc[i] = 0.f;
  __syncthreads();
  int cg = tid&15, rg = tid>>4;
  int c0 = cg*4, c1 = 64 + cg*4, row_g = rg*8;
  float acc[8][8];
  #pragma unroll
  for(int r=0;r<8;r++)
    #pragma unroll
    for(int c=0;c<8;c++) acc[r][c]=0.f;
  for(int k=0;k<64;k++){
    float4 w0 = *(const float4*)&Ws[k*128 + c0];
    float4 w1 = *(const float4*)&Ws[k*128 + c1];
    float xr[8];
    #pragma unroll
    for(int r=0;r<8;r++) xr[r] = xs[(row_g+r)*65 + k];
    #pragma unroll
    for(int r=0;r<8;r++){
      acc[r][0] += xr[r]*w0.x; acc[r][1] += xr[r]*w0.y;
      acc[r][2] += xr[r]*w0.z; acc[r][3] += xr[r]*w0.w;
      acc[r][4] += xr[r]*w1.x; acc[r][5] += xr[r]*w1.y;
      acc[r][6] += xr[r]*w1.z; acc[r][7] += xr[r]*w1.w;
    }
  }
  #pragma unroll
  for(int c=0;c<8;c++){
    int col = (c<4) ? (c0+c) : (c1+c-4);
    float bb = loadF(b, col, f32);
    #pragma unroll
    for(int r=0;r<8;r++){ float z = acc[r][c]+bb; acc[r][c] = z>0.f?z:0.f; }
  }
  int nv = N - row0; nv = nv < 128 ? nv : 128;
  if(nv <= 0) return;
  int gmin = gid[0], gmax = gid[nv-1];
  bool ldsOK = (NOUT <= 4) && (gmax - gmin < 128);
  for(int o=0;o<NOUT;o++){
    float fw[8];
    #pragma unroll
    for(int c=0;c<8;c++){
      int col = (c<4) ? (c0+c) : (c1+c-4);
      fw[c] = loadF(fcW, (long long)col*NOUT + o, f32);
    }
    #pragma unroll
    for(int r=0;r<8;r++){
      float z = acc[r][0]*fw[0] + acc[r][1]*fw[1] + acc[r][2]*fw[2] + acc[r][3]*fw[3]
              + acc[r][4]*fw[4] + acc[r][5]*fw[5] + acc[r][6]*fw[6] + acc[r][7]*fw[7];
      #pragma unroll
      for(int m=1;m<16;m<<=1) z += __shfl_xor(z, m, 64);
      int nl = row_g + r;
      if(cg==0 && nl < nv){
        int gg = gid[nl];
        if(ldsOK) atomicAdd(&Sloc[(gg-gmin)*NOUT + o], z);
        else      atomicAdd(&S[(long long)gg*NOUT + o], z);
      }
    }
  }
  if(ldsOK){
    __syncthreads();
    int nbin = (gmax - gmin + 1)*NOUT;
    for(int i=tid; i<nbin; i+=256){
      float v = Sloc[i];
      if(v != 0.f){
        int bin = i / NOUT, o = i - bin*NOUT;
        atomicAdd(&S[(long long)(gmin+bin)*NOUT + o], v);
      }
    }
  }
}

// ---------------- final: out[g,o] = S[g,o]/count_g + fcb[o] ----------------
static __device__ __forceinline__ int lower_bound_batch(const void* batch, int N, int key, int i64){
  int lo = 0, hi = N;
  while(lo < hi){ int mid = (lo+hi)>>1; if(loadI(batch, mid, i64) < key) lo = mid+1; else hi = mid; }
  return lo;
}

__global__ void k_final2(const float* __restrict__ S, const void* __restrict__ batch, int N,
                         const int* __restrict__ flags, const void* __restrict__ fcb,
                         void* __restrict__ out, int G, int NOUT){
  int f32 = flags[0], i64 = flags[1];
  int g = blockIdx.x*256 + threadIdx.x;
  if(g >= G) return;
  int c = lower_bound_batch(batch, N, g+1, i64) - lower_bound_batch(batch, N, g, i64);
  float inv = 1.f / (float)(c > 0 ? c : 1);
  for(int o=0;o<NOUT;o++){
    float r = S[(long long)g*NOUT+o]*inv + loadF(fcb, o, f32);
    if(f32) ((float*)out)[g*NOUT+o] = r;
    else    ((unsigned short*)out)[g*NOUT+o] = f2bf(r);
  }
}

extern "C" void kernel_launch(void* const* d_in, const int* in_sizes, int n_in,
                              void* d_out, int out_size, void* d_ws, size_t ws_size,
                              hipStream_t stream) {
  const void* x    = d_in[0];
  const void* ei   = d_in[1];
  const void* batch= d_in[2];
  const void* W1   = d_in[3];
  const void* b1   = d_in[4];
  const void* W2   = d_in[5];
  const void* b2   = d_in[6];
  const void* fcW  = d_in[7];
  const void* fcb  = d_in[8];

  const int N = in_sizes[0] / 64;       // 50000 (sentinel packing requires N <= 65535)
  const int E = in_sizes[1] / 2;        // 800000
  const int NOUT = in_sizes[8];         // 1
  const int G = out_size / NOUT;        // 128
  const int nbuckets = (N + 63) >> 6;   // 782

  size_t off = 0;
  auto alloc = [&](size_t bytes) -> char* {
    char* p = (char*)d_ws + off;
    off += (bytes + 511) & ~(size_t)511;
    return p;
  };
  int*   flags   = (int*)  alloc(512);
  int*   gcursor = (int*)  alloc((size_t)nbuckets*4);
  float* dinv    = (float*)alloc((size_t)N*4);
  int*   beg     = (int*)  alloc((size_t)N*4);
  int*   endv    = (int*)  alloc((size_t)N*4);
  float* S       = (float*)alloc((size_t)G*NOUT*4);
  unsigned int*   log  = (unsigned int*)  alloc((size_t)nbuckets*CAP*4);  // 12.8 MB
  unsigned short* csr  = (unsigned short*)alloc((size_t)nbuckets*CAP*2);  // 6.4 MB
  unsigned int*   g0   = (unsigned int*)  alloc((size_t)(N+1)*32*4);      // 6.4 MB, 2 planes
  unsigned int*   g1   = (unsigned int*)  alloc((size_t)(N+1)*32*4);      // 6.4 MB, 2 planes
  unsigned int*   aBuf = (unsigned int*)  alloc((size_t)N*32*4);          // 6.4 MB bf16 [N,64] linear
  (void)ws_size; (void)n_in;

  int initgrid = (nbuckets > G*NOUT ? nbuckets : G*NOUT);
  int nbpp = (N + 3) / 4;               // agg blocks per plane

  k_init    <<<(initgrid+255)/256, 256, 0, stream>>>((const unsigned int*)x, (const unsigned int*)ei,
                                                     flags, gcursor, nbuckets, S, G*NOUT, g0, g1, N);
  k_logbuild<<<(E+LB_EDGES-1)/LB_EDGES, 256, 0, stream>>>(ei, E, N, flags, gcursor, log, nbuckets);
  k_bsortg0 <<<nbuckets,      256, 0, stream>>>(log, gcursor, csr, beg, endv, dinv, x, flags, g0, N);

  k_agg     <<<2*nbpp,        256, 0, stream>>>(g0, csr, beg, endv, dinv, aBuf, N, nbpp);   // a1
  k_gemm1   <<<(N+127)/128,   256, 0, stream>>>(aBuf, W1, b1, flags, dinv, g1, N);          // g1 planes
  k_agg     <<<2*nbpp,        256, 0, stream>>>(g1, csr, beg, endv, dinv, aBuf, N, nbpp);   // a2
  k_gemm2pool<<<(N+127)/128,  256, 0, stream>>>(aBuf, W2, b2, fcW, batch, flags, S, N, NOUT);

  k_final2  <<<(G+255)/256,   256, 0, stream>>>(S, batch, N, flags, fcb, d_out, G, NOUT);
}

// Round 13
// 211.584 us; speedup vs baseline: 1.0989x; 1.0989x over previous
//
#include <hip/hip_runtime.h>
#include <hip/hip_bf16.h>

typedef __hip_bfloat16 bf16;

// flags[0] = 1 if floats are f32 (else bf16); flags[1] = 1 if ints are int64 (else int32)
static __device__ __forceinline__ float loadF(const void* p, long long i, int f32){
  return f32 ? ((const float*)p)[i] : __bfloat162float(((const bf16*)p)[i]);
}
static __device__ __forceinline__ int loadI(const void* p, long long i, int i64){
  return i64 ? (int)((const long long*)p)[i] : ((const int*)p)[i];
}
// round-to-nearest-even float -> bf16 bits (finite inputs)
static __device__ __forceinline__ unsigned short f2bf(float f){
  unsigned u = __float_as_uint(f);
  return (unsigned short)((u + 0x7FFFu + ((u>>16)&1u)) >> 16);
}
static __device__ __forceinline__ float bf2f(unsigned v){
  return __uint_as_float(v<<16);
}

#define CAP 4096        // log entries per bucket (avg ~1023)
#define LB_EDGES 4096   // edges per logbuild block

// ---------------- init: zero cursors + S + dtype sniff (block 0) ----------------
__global__ void k_init(const unsigned int* __restrict__ xw, const unsigned int* __restrict__ eiw,
                       int* __restrict__ flags, int* __restrict__ gcursor, int nbuckets,
                       float* __restrict__ S, int gn){
  int i = blockIdx.x*256 + threadIdx.x;
  if(i < nbuckets) gcursor[i] = 0;
  if(i < gn) S[i] = 0.f;
  if(blockIdx.x == 0){
    __shared__ int s1, s2;
    if(threadIdx.x==0){ s1=0; s2=0; }
    __syncthreads();
    unsigned w = xw[threadIdx.x];
    int e = (int)((w>>7)&0xFFu);
    if(e>=110 && e<=135) atomicAdd(&s1, 1);            // bf16-pair exponent signature
    if(eiw[2*threadIdx.x+1] != 0u) atomicAdd(&s2, 1);  // int64 high words
    __syncthreads();
    if(threadIdx.x==0){
      flags[0] = (s1 < 128) ? 1 : 0;   // 1 => f32
      flags[1] = (s2 < 128) ? 1 : 0;   // 1 => int64
    }
  }
}

// ---------------- bucket-log build: packed (dst<<16)|src, grouped by dst>>6 ----------------
__global__ __launch_bounds__(256) void k_logbuild(const void* __restrict__ ei, int E, int N,
                                                  const int* __restrict__ flags,
                                                  int* __restrict__ gcursor,
                                                  unsigned int* __restrict__ log, int nbuckets){
  __shared__ unsigned int stash[LB_EDGES];   // 16 KB
  __shared__ int hcnt[1024];
  __shared__ int hbase[1024];
  int t = threadIdx.x;
  for(int b=t; b<nbuckets; b+=256) hcnt[b] = 0;
  __syncthreads();
  int i64 = flags[1];
  long long e0 = (long long)blockIdx.x*LB_EDGES;
  int cnt = (int)(((long long)E - e0) < LB_EDGES ? ((long long)E - e0) : LB_EDGES);
  for(int k=t; k<cnt; k+=256){
    long long e = e0 + k;
    int s = loadI(ei, e, i64);                 s = min(max(s,0), N-1);
    int d = loadI(ei, (long long)E + e, i64);  d = min(max(d,0), N-1);
    unsigned p = (((unsigned)d)<<16) | (unsigned)s;   // requires N <= 65536
    stash[k] = p;
    atomicAdd(&hcnt[d>>6], 1);
  }
  __syncthreads();
  for(int b=t; b<nbuckets; b+=256){
    int c = hcnt[b];
    hbase[b] = (c>0) ? atomicAdd(&gcursor[b], c) : 0;
    hcnt[b] = 0;
  }
  __syncthreads();
  for(int k=t; k<cnt; k+=256){
    unsigned p = stash[k];
    int b = (int)(p>>22);                      // dst>>6
    int pos = hbase[b] + atomicAdd(&hcnt[b], 1);
    if(pos < CAP) log[(long long)b*CAP + pos] = p;
  }
}

// ---------------- per-bucket counting sort + dinv + g0 for the bucket's 64 nodes ----------------
__global__ __launch_bounds__(256) void k_bsortg0(const unsigned int* __restrict__ log,
                                                 const int* __restrict__ gcursor,
                                                 unsigned short* __restrict__ csr,
                                                 int* __restrict__ beg, int* __restrict__ endv,
                                                 float* __restrict__ dinv,
                                                 const void* __restrict__ x, const int* __restrict__ flags,
                                                 unsigned short* __restrict__ g0, int N){
  __shared__ int hist[64];
  __shared__ int cur[64];
  __shared__ float dloc[64];
  int b = blockIdx.x, t = threadIdx.x;
  if(t < 64) hist[t] = 0;
  __syncthreads();
  int n = min(gcursor[b], CAP);
  const unsigned int* L = log + (long long)b*CAP;
  for(int j=t; j<n; j+=256) atomicAdd(&hist[(L[j]>>16)&63], 1);
  __syncthreads();
  if(t < 64){                                   // wave 0: exclusive scan over 64 bins
    int v = hist[t];
    int inc = v;
    #pragma unroll
    for(int o=1; o<64; o<<=1){
      int u = __shfl_up(inc, o);
      if(t >= o) inc += u;
    }
    int excl = inc - v;
    cur[t] = excl;
    float dv = rsqrtf((float)(v + 1));          // +1 = self loop
    dloc[t] = dv;
    int node = b*64 + t;
    if(node < N){
      int base = b*CAP + excl;
      beg[node]  = base;
      endv[node] = base + v;
      dinv[node] = dv;
    }
  }
  __syncthreads();
  unsigned short* C = csr + (long long)b*CAP;
  for(int j=t; j<n; j+=256){
    unsigned p = L[j];
    int l = (int)((p>>16)&63u);
    int pos = atomicAdd(&cur[l], 1);
    C[pos] = (unsigned short)(p & 0xFFFFu);
  }
  // g0 for this bucket's nodes: g0 = bf16(x * dinv)
  int f32 = flags[0];
  long long base = (long long)b*64*64;
  for(int i=t; i<4096; i+=256){
    int nl = i>>6;
    int node = b*64 + nl;
    if(node < N) g0[base + i] = f2bf(loadF(x, base + i, f32) * dloc[nl]);
  }
}

// ---------------- AGG: a[d] = bf16( dinv[d]*(sum_{s in N(d)} g[s] + g[d]) ); wave per node ----------------
// dword-pair loads: lane half 0/1 handles even/odd edges; 8 gathers in flight
__global__ __launch_bounds__(256) void k_agg(const unsigned short* __restrict__ g,
                                             const unsigned short* __restrict__ csr,
                                             const int* __restrict__ beg, const int* __restrict__ endv,
                                             const float* __restrict__ dinv,
                                             unsigned int* __restrict__ out32, int N){
  int node = blockIdx.x*4 + (threadIdx.x>>6);
  int lane = threadIdx.x&63;
  if(node >= N) return;
  int half = lane>>5, fl = lane&31;
  const unsigned int* G32 = (const unsigned int*)g;   // row = 32 dwords (64 bf16)
  int j = beg[node], e = endv[node];
  float2 a0={0.f,0.f}, a1={0.f,0.f}, a2={0.f,0.f}, a3={0.f,0.f};
  float2 a4={0.f,0.f}, a5={0.f,0.f}, a6={0.f,0.f}, a7={0.f,0.f};
  for(; j+16<=e; j+=16){                              // 16 edges/iter, 8 loads in flight
    int s0 = csr[j +  0 + half];
    int s1 = csr[j +  2 + half];
    int s2 = csr[j +  4 + half];
    int s3 = csr[j +  6 + half];
    int s4 = csr[j +  8 + half];
    int s5 = csr[j + 10 + half];
    int s6 = csr[j + 12 + half];
    int s7 = csr[j + 14 + half];
    unsigned v0 = G32[(long long)s0*32 + fl];
    unsigned v1 = G32[(long long)s1*32 + fl];
    unsigned v2 = G32[(long long)s2*32 + fl];
    unsigned v3 = G32[(long long)s3*32 + fl];
    unsigned v4 = G32[(long long)s4*32 + fl];
    unsigned v5 = G32[(long long)s5*32 + fl];
    unsigned v6 = G32[(long long)s6*32 + fl];
    unsigned v7 = G32[(long long)s7*32 + fl];
    a0.x += bf2f(v0 & 0xFFFFu); a0.y += bf2f(v0 >> 16);
    a1.x += bf2f(v1 & 0xFFFFu); a1.y += bf2f(v1 >> 16);
    a2.x += bf2f(v2 & 0xFFFFu); a2.y += bf2f(v2 >> 16);
    a3.x += bf2f(v3 & 0xFFFFu); a3.y += bf2f(v3 >> 16);
    a4.x += bf2f(v4 & 0xFFFFu); a4.y += bf2f(v4 >> 16);
    a5.x += bf2f(v5 & 0xFFFFu); a5.y += bf2f(v5 >> 16);
    a6.x += bf2f(v6 & 0xFFFFu); a6.y += bf2f(v6 >> 16);
    a7.x += bf2f(v7 & 0xFFFFu); a7.y += bf2f(v7 >> 16);
  }
  for(; j+8<=e; j+=8){                                // 8 edges/iter tail
    int s0 = csr[j + 0 + half];
    int s1 = csr[j + 2 + half];
    int s2 = csr[j + 4 + half];
    int s3 = csr[j + 6 + half];
    unsigned v0 = G32[(long long)s0*32 + fl];
    unsigned v1 = G32[(long long)s1*32 + fl];
    unsigned v2 = G32[(long long)s2*32 + fl];
    unsigned v3 = G32[(long long)s3*32 + fl];
    a0.x += bf2f(v0 & 0xFFFFu); a0.y += bf2f(v0 >> 16);
    a1.x += bf2f(v1 & 0xFFFFu); a1.y += bf2f(v1 >> 16);
    a2.x += bf2f(v2 & 0xFFFFu); a2.y += bf2f(v2 >> 16);
    a3.x += bf2f(v3 & 0xFFFFu); a3.y += bf2f(v3 >> 16);
  }
  for(; j+2<=e; j+=2){
    int s = csr[j + half];
    unsigned v = G32[(long long)s*32 + fl];
    a0.x += bf2f(v & 0xFFFFu); a0.y += bf2f(v >> 16);
  }
  if(j < e && half == 0){
    int s = csr[j];
    unsigned v = G32[(long long)s*32 + fl];
    a0.x += bf2f(v & 0xFFFFu); a0.y += bf2f(v >> 16);
  }
  float sx = ((a0.x+a1.x)+(a2.x+a3.x)) + ((a4.x+a5.x)+(a6.x+a7.x));
  float sy = ((a0.y+a1.y)+(a2.y+a3.y)) + ((a4.y+a5.y)+(a6.y+a7.y));
  sx += __shfl_xor(sx, 32, 64);                       // combine even/odd halves
  sy += __shfl_xor(sy, 32, 64);
  unsigned sv = G32[(long long)node*32 + fl];         // self term
  float dv = dinv[node];
  sx = (sx + bf2f(sv & 0xFFFFu)) * dv;
  sy = (sy + bf2f(sv >> 16)) * dv;
  if(half == 0)
    out32[(long long)node*32 + fl] = (unsigned)f2bf(sx) | ((unsigned)f2bf(sy) << 16);
}

// ---------------- GEMM1: g1 = bf16(relu(a @ W1 + b1) * dinv[row]), [N,64]; a is bf16 ----------------
// tile: 128 rows x 64 cols, 256 threads, R=8 C=4 per thread
__global__ __launch_bounds__(256) void k_gemm1(const unsigned int* __restrict__ A32, const void* __restrict__ W,
                                               const void* __restrict__ b, const int* __restrict__ flags,
                                               const float* __restrict__ dinv, unsigned short* __restrict__ out, int N){
  __shared__ float Ws[64*64];
  __shared__ float xs[128*65];
  int f32 = flags[0];
  int tid = threadIdx.x;
  for(int i=tid;i<4096;i+=256) Ws[i] = loadF(W, i, f32);
  int row0 = blockIdx.x*128;
  for(int i=tid;i<4096;i+=256){                 // 4096 dwords = 128 rows x 32 dwords
    int r = i>>5, kd = i&31;
    int gr = row0 + r;
    unsigned v = (gr<N) ? A32[(long long)gr*32 + kd] : 0u;
    xs[r*65 + 2*kd    ] = bf2f(v & 0xFFFFu);
    xs[r*65 + 2*kd + 1] = bf2f(v >> 16);
  }
  __syncthreads();
  int cg = tid&15, rg = tid>>4;
  int col_g = cg*4, row_g = rg*8;
  float acc[8][4];
  #pragma unroll
  for(int r=0;r<8;r++){ acc[r][0]=0.f; acc[r][1]=0.f; acc[r][2]=0.f; acc[r][3]=0.f; }
  for(int k=0;k<64;k++){
    float4 w = *(const float4*)&Ws[k*64 + col_g];
    float xr[8];
    #pragma unroll
    for(int r=0;r<8;r++) xr[r] = xs[(row_g+r)*65 + k];
    #pragma unroll
    for(int r=0;r<8;r++){
      acc[r][0] += xr[r]*w.x; acc[r][1] += xr[r]*w.y;
      acc[r][2] += xr[r]*w.z; acc[r][3] += xr[r]*w.w;
    }
  }
  float b0 = loadF(b, col_g,   f32), b1v = loadF(b, col_g+1, f32);
  float b2v = loadF(b, col_g+2, f32), b3 = loadF(b, col_g+3, f32);
  #pragma unroll
  for(int r=0;r<8;r++){
    int gr = row0 + row_g + r;
    if(gr<N){
      float dv = dinv[gr];
      float v0 = acc[r][0]+b0, v1 = acc[r][1]+b1v, v2 = acc[r][2]+b2v, v3 = acc[r][3]+b3;
      v0 = (v0>0.f?v0:0.f)*dv; v1 = (v1>0.f?v1:0.f)*dv;
      v2 = (v2>0.f?v2:0.f)*dv; v3 = (v3>0.f?v3:0.f)*dv;
      ushort4 st;
      st.x = f2bf(v0); st.y = f2bf(v1); st.z = f2bf(v2); st.w = f2bf(v3);
      *(ushort4*)&out[(long long)gr*64 + col_g] = st;
    }
  }
}

// ---------------- fused GEMM2 + relu + fcW-dot + mean-pool partials; a is bf16 ----------------
// tile: 128 rows x 128 cols; thread covers 8 rows x cols {4cg..4cg+3, 64+4cg..+3}
// Ws b128 starts 4cg mod 32 -> 2-way free; xs uniform-k broadcasts free.
__global__ __launch_bounds__(256) void k_gemm2pool(const unsigned int* __restrict__ A32, const void* __restrict__ W,
                                                   const void* __restrict__ b, const void* __restrict__ fcW,
                                                   const void* __restrict__ batch, const int* __restrict__ flags,
                                                   float* __restrict__ S, int N, int NOUT){
  __shared__ float Ws[64*128];     // 32 KB
  __shared__ float xs[128*65];     // 32.5 KB
  __shared__ float Sloc[128*4];
  __shared__ int gid[128];
  int f32 = flags[0], i64 = flags[1];
  int tid = threadIdx.x;
  int row0 = blockIdx.x*128;
  for(int i=tid;i<8192;i+=256) Ws[i] = loadF(W, i, f32);
  for(int i=tid;i<4096;i+=256){                 // 4096 dwords = 128 rows x 32 dwords
    int r = i>>5, kd = i&31;
    int gr = row0 + r;
    unsigned v = (gr<N) ? A32[(long long)gr*32 + kd] : 0u;
    xs[r*65 + 2*kd    ] = bf2f(v & 0xFFFFu);
    xs[r*65 + 2*kd + 1] = bf2f(v >> 16);
  }
  if(tid < 128){
    int node = row0 + tid;
    gid[tid] = (node < N) ? loadI(batch, node, i64) : 0;
  }
  for(int i=tid;i<512;i+=256) Sloc[i] = 0.f;
  __syncthreads();
  int cg = tid&15, rg = tid>>4;
  int c0 = cg*4, c1 = 64 + cg*4, row_g = rg*8;
  float acc[8][8];
  #pragma unroll
  for(int r=0;r<8;r++)
    #pragma unroll
    for(int c=0;c<8;c++) acc[r][c]=0.f;
  for(int k=0;k<64;k++){
    float4 w0 = *(const float4*)&Ws[k*128 + c0];
    float4 w1 = *(const float4*)&Ws[k*128 + c1];
    float xr[8];
    #pragma unroll
    for(int r=0;r<8;r++) xr[r] = xs[(row_g+r)*65 + k];
    #pragma unroll
    for(int r=0;r<8;r++){
      acc[r][0] += xr[r]*w0.x; acc[r][1] += xr[r]*w0.y;
      acc[r][2] += xr[r]*w0.z; acc[r][3] += xr[r]*w0.w;
      acc[r][4] += xr[r]*w1.x; acc[r][5] += xr[r]*w1.y;
      acc[r][6] += xr[r]*w1.z; acc[r][7] += xr[r]*w1.w;
    }
  }
  // bias + relu in registers
  #pragma unroll
  for(int c=0;c<8;c++){
    int col = (c<4) ? (c0+c) : (c1+c-4);
    float bb = loadF(b, col, f32);
    #pragma unroll
    for(int r=0;r<8;r++){ float z = acc[r][c]+bb; acc[r][c] = z>0.f?z:0.f; }
  }
  // fcW dot + pooled partial sums
  int nv = N - row0; nv = nv < 128 ? nv : 128;
  if(nv <= 0) return;
  int gmin = gid[0], gmax = gid[nv-1];
  bool ldsOK = (NOUT <= 4) && (gmax - gmin < 128);
  for(int o=0;o<NOUT;o++){
    float fw[8];
    #pragma unroll
    for(int c=0;c<8;c++){
      int col = (c<4) ? (c0+c) : (c1+c-4);
      fw[c] = loadF(fcW, (long long)col*NOUT + o, f32);
    }
    #pragma unroll
    for(int r=0;r<8;r++){
      float z = acc[r][0]*fw[0] + acc[r][1]*fw[1] + acc[r][2]*fw[2] + acc[r][3]*fw[3]
              + acc[r][4]*fw[4] + acc[r][5]*fw[5] + acc[r][6]*fw[6] + acc[r][7]*fw[7];
      #pragma unroll
      for(int m=1;m<16;m<<=1) z += __shfl_xor(z, m, 64);
      int nl = row_g + r;
      if(cg==0 && nl < nv){
        int gg = gid[nl];
        if(ldsOK) atomicAdd(&Sloc[(gg-gmin)*NOUT + o], z);
        else      atomicAdd(&S[(long long)gg*NOUT + o], z);
      }
    }
  }
  if(ldsOK){
    __syncthreads();
    int nbin = (gmax - gmin + 1)*NOUT;
    for(int i=tid; i<nbin; i+=256){
      float v = Sloc[i];
      if(v != 0.f){
        int bin = i / NOUT, o = i - bin*NOUT;
        atomicAdd(&S[(long long)(gmin+bin)*NOUT + o], v);
      }
    }
  }
}

// ---------------- final: out[g,o] = S[g,o]/count_g + fcb[o] ----------------
static __device__ __forceinline__ int lower_bound_batch(const void* batch, int N, int key, int i64){
  int lo = 0, hi = N;
  while(lo < hi){ int mid = (lo+hi)>>1; if(loadI(batch, mid, i64) < key) lo = mid+1; else hi = mid; }
  return lo;
}

__global__ void k_final2(const float* __restrict__ S, const void* __restrict__ batch, int N,
                         const int* __restrict__ flags, const void* __restrict__ fcb,
                         void* __restrict__ out, int G, int NOUT){
  int f32 = flags[0], i64 = flags[1];
  int g = blockIdx.x*256 + threadIdx.x;
  if(g >= G) return;
  int c = lower_bound_batch(batch, N, g+1, i64) - lower_bound_batch(batch, N, g, i64);
  float inv = 1.f / (float)(c > 0 ? c : 1);
  for(int o=0;o<NOUT;o++){
    float r = S[(long long)g*NOUT+o]*inv + loadF(fcb, o, f32);
    if(f32) ((float*)out)[g*NOUT+o] = r;
    else    ((unsigned short*)out)[g*NOUT+o] = f2bf(r);
  }
}

extern "C" void kernel_launch(void* const* d_in, const int* in_sizes, int n_in,
                              void* d_out, int out_size, void* d_ws, size_t ws_size,
                              hipStream_t stream) {
  const void* x    = d_in[0];
  const void* ei   = d_in[1];
  const void* batch= d_in[2];
  const void* W1   = d_in[3];
  const void* b1   = d_in[4];
  const void* W2   = d_in[5];
  const void* b2   = d_in[6];
  const void* fcW  = d_in[7];
  const void* fcb  = d_in[8];

  const int N = in_sizes[0] / 64;       // 50000 (packing requires N <= 65536)
  const int E = in_sizes[1] / 2;        // 800000
  const int NOUT = in_sizes[8];         // 1
  const int G = out_size / NOUT;        // 128
  const int nbuckets = (N + 63) >> 6;   // 782

  size_t off = 0;
  auto alloc = [&](size_t bytes) -> char* {
    char* p = (char*)d_ws + off;
    off += (bytes + 511) & ~(size_t)511;
    return p;
  };
  int*   flags   = (int*)  alloc(512);
  int*   gcursor = (int*)  alloc((size_t)nbuckets*4);
  float* dinv    = (float*)alloc((size_t)N*4);
  int*   beg     = (int*)  alloc((size_t)N*4);
  int*   endv    = (int*)  alloc((size_t)N*4);
  float* S       = (float*)alloc((size_t)G*NOUT*4);
  unsigned int*   log  = (unsigned int*)  alloc((size_t)nbuckets*CAP*4);  // 12.8 MB
  unsigned short* csr  = (unsigned short*)alloc((size_t)nbuckets*CAP*2);  // 6.4 MB
  unsigned short* g0   = (unsigned short*)alloc((size_t)N*64*2);          // 6.4 MB
  unsigned short* g1   = (unsigned short*)alloc((size_t)N*64*2);          // 6.4 MB
  unsigned int*   aBuf = (unsigned int*)  alloc((size_t)N*32*4);          // 6.4 MB bf16 [N,64] (a1 then a2)
  (void)ws_size; (void)n_in;

  int initgrid = (nbuckets > G*NOUT ? nbuckets : G*NOUT);

  k_init    <<<(initgrid+255)/256, 256, 0, stream>>>((const unsigned int*)x, (const unsigned int*)ei,
                                                     flags, gcursor, nbuckets, S, G*NOUT);
  k_logbuild<<<(E+LB_EDGES-1)/LB_EDGES, 256, 0, stream>>>(ei, E, N, flags, gcursor, log, nbuckets);
  k_bsortg0 <<<nbuckets,      256, 0, stream>>>(log, gcursor, csr, beg, endv, dinv, x, flags, g0, N);

  k_agg     <<<(N+3)/4,       256, 0, stream>>>(g0, csr, beg, endv, dinv, aBuf, N);   // a1 (bf16)
  k_gemm1   <<<(N+127)/128,   256, 0, stream>>>(aBuf, W1, b1, flags, dinv, g1, N);    // g1
  k_agg     <<<(N+3)/4,       256, 0, stream>>>(g1, csr, beg, endv, dinv, aBuf, N);   // a2 (bf16)
  k_gemm2pool<<<(N+127)/128,  256, 0, stream>>>(aBuf, W2, b2, fcW, batch, flags, S, N, NOUT);

  k_final2  <<<(G+255)/256,   256, 0, stream>>>(S, batch, N, flags, fcb, d_out, G, NOUT);
}